// Round 1
// baseline (54.362 us; speedup 1.0000x reference)
//
#include <hip/hip_runtime.h>

// Problem constants (from the reference module, compile-time):
//   NPOSES=16, NBLOCKS=1024, ATOMS_PER_BLOCK=16, N_CNSTRS=3, IDEAL=4.0
//   _CNSTR_ATOMS[0] = {(0,0),(1,1)};  _CNSTR_ATOMS[1] = {(1,0),(2,1)};
//   _CNSTR_ATOMS[2] = {(0,0),(1,1)};  _CNSTR_POSE = {0,0,0}
// Only atoms 0 and 1 of each constraint are used (diff of the pair).
// Output: (1,16) fp32; out[p] = sum over constraints c with pose==p of
//   (|| x0 - x1 || - 4)^2

#define NPOSES 16
#define NBLOCKS 1024
#define ATOMS_PER_BLOCK 16
#define N_CNSTRS 3

__global__ void cnstr_score_kernel(const float* __restrict__ coords,
                                   const int* __restrict__ block_coord_offset,
                                   float* __restrict__ out) {
    const int p = threadIdx.x;
    if (p >= NPOSES) return;

    // hardcoded constraint topology
    const int cpose[N_CNSTRS] = {0, 0, 0};
    const int res0[N_CNSTRS]  = {0, 1, 0};
    const int atm0[N_CNSTRS]  = {0, 0, 0};
    const int res1[N_CNSTRS]  = {1, 2, 1};
    const int atm1[N_CNSTRS]  = {1, 1, 1};

    float acc = 0.0f;
    #pragma unroll
    for (int c = 0; c < N_CNSTRS; ++c) {
        if (cpose[c] != p) continue;
        const int pose = cpose[c];
        const int g0 = block_coord_offset[pose * NBLOCKS + res0[c]] + atm0[c];
        const int g1 = block_coord_offset[pose * NBLOCKS + res1[c]] + atm1[c];
        const float* a = coords + ((long)pose * (NBLOCKS * ATOMS_PER_BLOCK) + g0) * 3;
        const float* b = coords + ((long)pose * (NBLOCKS * ATOMS_PER_BLOCK) + g1) * 3;
        const float dx = a[0] - b[0];
        const float dy = a[1] - b[1];
        const float dz = a[2] - b[2];
        const float d  = sqrtf(dx * dx + dy * dy + dz * dz) - 4.0f;
        acc += d * d;
    }
    out[p] = acc;
}

extern "C" void kernel_launch(void* const* d_in, const int* in_sizes, int n_in,
                              void* d_out, int out_size, void* d_ws, size_t ws_size,
                              hipStream_t stream) {
    const float* coords = (const float*)d_in[0];
    const int* block_coord_offset = (const int*)d_in[1];
    float* out = (float*)d_out;
    // one wave: lanes 0..15 each own one pose's output element
    cnstr_score_kernel<<<1, 64, 0, stream>>>(coords, block_coord_offset, out);
}